// Round 8
// baseline (206.346 us; speedup 1.0000x reference)
//
#include <hip/hip_runtime.h>
#include <hip/hip_bf16.h>

typedef short bf16x8 __attribute__((ext_vector_type(8)));
typedef short bf16x4 __attribute__((ext_vector_type(4)));
typedef float f32x4 __attribute__((ext_vector_type(4)));
typedef unsigned short u16x8 __attribute__((ext_vector_type(8)));
typedef unsigned short u16x4 __attribute__((ext_vector_type(4)));

#define DEV static __device__ __forceinline__

DEV unsigned short f2bf(float f) {
  unsigned int u = __builtin_bit_cast(unsigned int, f);
  u += 0x7FFFu + ((u >> 16) & 1u);   // round-to-nearest-even
  return (unsigned short)(u >> 16);
}
DEV float bf2f(unsigned short u) {
  return __builtin_bit_cast(float, (unsigned int)u << 16);
}

DEV void gload_lds16(const unsigned short* g, unsigned short* l) {
  __builtin_amdgcn_global_load_lds(
      (const __attribute__((address_space(1))) unsigned int*)g,
      (__attribute__((address_space(3))) unsigned int*)l, 16, 0, 0);
}

DEV void waitv(int n) {   // n is compile-time under full unroll -> folds
  switch (n) {
    case 0: asm volatile("s_waitcnt vmcnt(0)" ::: "memory"); break;
    case 1: asm volatile("s_waitcnt vmcnt(1)" ::: "memory"); break;
    case 2: asm volatile("s_waitcnt vmcnt(2)" ::: "memory"); break;
    case 4: asm volatile("s_waitcnt vmcnt(4)" ::: "memory"); break;
    case 6: asm volatile("s_waitcnt vmcnt(6)" ::: "memory"); break;
    default: asm volatile("s_waitcnt vmcnt(0)" ::: "memory"); break;
  }
}

#define SB() __builtin_amdgcn_sched_barrier(0)
#define BAR() do { __builtin_amdgcn_s_barrier(); SB(); } while (0)
#define LBAR() do { asm volatile("s_waitcnt lgkmcnt(0)" ::: "memory"); \
                    SB(); \
                    __builtin_amdgcn_s_barrier(); \
                    SB(); } while (0)
#define PRIO1() __builtin_amdgcn_s_setprio(1)
#define PRIO0() __builtin_amdgcn_s_setprio(0)

// ---------------------------------------------------------------------------
// Fused projection GEMMs, f32 inputs (conversion fused into staging).
// seg = blockIdx>>8 picks (X, W, bias, out, mode). 128x128 tile, BK=64,
// 512 threads (8 waves, 2m x 4n). Reg-staged f32->bf16 with both-sides XOR
// unit swizzle (kills the 16-way row-stride-128B bank conflict).
// XCD swizzle: the 8 n-blocks of one m-row land on one XCD (X L2 reuse).
// mode 0: bf16 row-major. mode 2: bf16 transposed per-head (V).
// ---------------------------------------------------------------------------
__global__ __launch_bounds__(512) void gemm_kernel(
    const float* __restrict__ xq, const float* __restrict__ xk,
    const float* __restrict__ xv, const float* __restrict__ wqf,
    const float* __restrict__ wkf, const float* __restrict__ wvf,
    const float* __restrict__ bq, const float* __restrict__ bk,
    const float* __restrict__ bv, unsigned short* __restrict__ qp,
    unsigned short* __restrict__ kp, unsigned short* __restrict__ vt)
{
  __shared__ union {
    struct { unsigned short A[128][64]; unsigned short B[128][64]; } ab;
    unsigned short T[128][132];        // +4 pad: bank spread for epilogue
  } smu;
  const int t = threadIdx.x, lane = t & 63, wv8 = t >> 6;
  const int ln = lane & 15, g = lane >> 4;
  const int wm2 = wv8 >> 2, wn4 = wv8 & 3;
  const int seg = blockIdx.x >> 8, lb = blockIdx.x & 255;
  const int x8 = lb & 7, s32 = lb >> 3;             // xcd, intra-xcd index
  const int m0 = (x8 * 4 + (s32 >> 3)) * 128;       // same-m blocks share XCD
  const int n0 = (s32 & 7) * 128;

  const float* X; const float* W; const float* bias;
  unsigned short* outR; int mode;
  if (seg == 0)      { X = xq; W = wqf; bias = bq; outR = qp; mode = 0; }
  else if (seg == 1) { X = xk; W = wkf; bias = bk; outR = kp; mode = 0; }
  else               { X = xv; W = wvf; bias = bv; outR = vt; mode = 2; }

  f32x4 acc[4][2];
#pragma unroll
  for (int i = 0; i < 4; ++i)
#pragma unroll
    for (int j = 0; j < 2; ++j) acc[i][j] = {0.f, 0.f, 0.f, 0.f};

  const int srow = t >> 2;           // 0..127 staging row
  const int su0 = (t & 3) * 2;       // first 8-elem unit (of 8 per row)
  const int swz = srow & 7;
  for (int kt = 0; kt < 16; ++kt) {
    const int k0 = kt * 64;
    __syncthreads();
    {
      const float* ga = X + (size_t)(m0 + srow) * 1024 + k0 + su0 * 8;
      float4 a0 = *(const float4*)ga;
      float4 a1 = *(const float4*)(ga + 4);
      float4 a2 = *(const float4*)(ga + 8);
      float4 a3 = *(const float4*)(ga + 12);
      u16x8 p0 = { f2bf(a0.x), f2bf(a0.y), f2bf(a0.z), f2bf(a0.w),
                   f2bf(a1.x), f2bf(a1.y), f2bf(a1.z), f2bf(a1.w) };
      u16x8 p1 = { f2bf(a2.x), f2bf(a2.y), f2bf(a2.z), f2bf(a2.w),
                   f2bf(a3.x), f2bf(a3.y), f2bf(a3.z), f2bf(a3.w) };
      *(u16x8*)&smu.ab.A[srow][(su0 ^ swz) * 8] = p0;
      *(u16x8*)&smu.ab.A[srow][((su0 + 1) ^ swz) * 8] = p1;
      const float* gb = W + (size_t)(n0 + srow) * 1024 + k0 + su0 * 8;
      float4 b0 = *(const float4*)gb;
      float4 b1 = *(const float4*)(gb + 4);
      float4 b2 = *(const float4*)(gb + 8);
      float4 b3 = *(const float4*)(gb + 12);
      u16x8 q0 = { f2bf(b0.x), f2bf(b0.y), f2bf(b0.z), f2bf(b0.w),
                   f2bf(b1.x), f2bf(b1.y), f2bf(b1.z), f2bf(b1.w) };
      u16x8 q1 = { f2bf(b2.x), f2bf(b2.y), f2bf(b2.z), f2bf(b2.w),
                   f2bf(b3.x), f2bf(b3.y), f2bf(b3.z), f2bf(b3.w) };
      *(u16x8*)&smu.ab.B[srow][(su0 ^ swz) * 8] = q0;
      *(u16x8*)&smu.ab.B[srow][((su0 + 1) ^ swz) * 8] = q1;
    }
    __syncthreads();
#pragma unroll
    for (int ks = 0; ks < 2; ++ks) {
      bf16x8 af[4], bfr[2];
      const int ru = (ks * 4 + g) ^ (ln & 7);   // swizzled read unit
#pragma unroll
      for (int i = 0; i < 4; ++i)
        af[i] = *(const bf16x8*)&smu.ab.A[wm2 * 64 + i * 16 + ln][ru * 8];
#pragma unroll
      for (int j = 0; j < 2; ++j)
        bfr[j] = *(const bf16x8*)&smu.ab.B[wn4 * 32 + j * 16 + ln][ru * 8];
      PRIO1();
#pragma unroll
      for (int i = 0; i < 4; ++i)
#pragma unroll
        for (int j = 0; j < 2; ++j)
          acc[i][j] = __builtin_amdgcn_mfma_f32_16x16x32_bf16(
              af[i], bfr[j], acc[i][j], 0, 0, 0);
      PRIO0();
    }
  }

  float bvv[2];
#pragma unroll
  for (int j = 0; j < 2; ++j) bvv[j] = bias[n0 + wn4 * 32 + j * 16 + ln];

  if (mode == 0) {
#pragma unroll
    for (int i = 0; i < 4; ++i)
#pragma unroll
      for (int j = 0; j < 2; ++j)
#pragma unroll
        for (int r = 0; r < 4; ++r) {
          int row = m0 + wm2 * 64 + i * 16 + g * 4 + r;
          int col = n0 + wn4 * 32 + j * 16 + ln;
          outR[(size_t)row * 1024 + col] = f2bf(acc[i][j][r] + bvv[j]);
        }
  } else {
    __syncthreads();   // A/B reads done; reuse LDS as T
#pragma unroll
    for (int i = 0; i < 4; ++i)
#pragma unroll
      for (int j = 0; j < 2; ++j)
#pragma unroll
        for (int r = 0; r < 4; ++r)
          smu.T[wn4 * 32 + j * 16 + ln][wm2 * 64 + i * 16 + g * 4 + r] =
              f2bf(acc[i][j][r] + bvv[j]);
    __syncthreads();
    const int bb = m0 >> 10, l0 = m0 & 1023;
#pragma unroll
    for (int it = 0; it < 4; ++it) {
      const int col = it * 32 + (t >> 4);
      const int r8 = (t & 15) * 8;
      *(u16x8*)&outR[((size_t)(bb * 16 + (n0 >> 6) + (col >> 6)) * 64 + (col & 63)) * 1024 + l0 + r8] =
          *(const u16x8*)&smu.T[col][r8];
    }
  }
}

// ---------------------------------------------------------------------------
// Attention: block = (b, h, 32 q-rows), 512 threads = 8 waves (4 wq x 2 wm).
// S^T = K*Q^T (validated mapping). QK: per-wave private K rings, zero
// barriers, self-paced counted vmcnt. Softmax: ONE barrier (local-max
// partial sums; normalization folded into the exponent). PV: shared 3-slot
// V ring, 1 barrier/chunk, counted vmcnt, attention stores interleaved.
// s_setprio(1) around MFMA clusters. Residual qp+ctx -> d_out.
// ---------------------------------------------------------------------------
__global__ __launch_bounds__(512, 2) void attn_kernel(
    const unsigned short* __restrict__ qp, const unsigned short* __restrict__ kp,
    const unsigned short* __restrict__ vt, const unsigned char* __restrict__ masks,
    float* __restrict__ attn_out, float* __restrict__ res_out)
{
  __shared__ union {
    unsigned short Kw[8][3][1024];   // per-wave K rings: [wave][slot][16*64]
    unsigned short Vb[3][64][128];   // shared V ring
    float ctxp[4][32][68];           // reduction phase (+4 pad: bank spread)
  } sm;
  __shared__ float red[2][2][16][4]; // [max/sum][wm][ln][wq]

  const int t = threadIdx.x;
  const int wv = t >> 6, lane = t & 63;
  const int ln = lane & 15, g = lane >> 4;
  const int wq = wv & 3, wm = wv >> 2;
  const int hw = blockIdx.x;
  const int lid = (hw & 7) * 256 + (hw >> 3);  // cluster same-(b,h) per XCD
  const int b = lid >> 9, h = (lid >> 5) & 15, m0 = (lid & 31) * 32;
  const size_t rowbase = (size_t)(b * 1024 + m0);

  // ---- Q fragments (oldest vmcnt entries; retired by the first QK waits) ----
  bf16x8 qf[2];
  {
    const unsigned short* qb =
        qp + (rowbase + wm * 16 + ln) * 1024 + h * 64 + g * 8;
    qf[0] = *(const bf16x8*)qb;
    qf[1] = *(const bf16x8*)(qb + 32);
  }
  SB();

  // staging geometry
  const int slr8 = lane >> 3;                // 0..7 local row (K chunks)
  const int suK = (lane & 7) ^ slr8;         // swizzled K source unit
  const int vlr = lane >> 4;                 // 0..3 local row (V chunks)
  const int vu1 = (lane & 15) ^ vlr;         // V source units (rows +0..3)
  const int vu2 = (lane & 15) ^ (4 + vlr);   //               (rows +4..7)
  const unsigned short* kbase = kp + (size_t)b * 1048576 + h * 64;
  const unsigned short* vtb = vt + ((size_t)(b * 16 + h) * 64) * 1024;
  unsigned short* kwv = &sm.Kw[wv][0][0];

#define STAGE_K(tt) do { \
    gload_lds16(kbase + (size_t)((tt) * 64 + wq * 16 + slr8) * 1024 + suK * 8, \
                kwv + ((tt) % 3) * 1024); \
    gload_lds16(kbase + (size_t)((tt) * 64 + wq * 16 + 8 + slr8) * 1024 + suK * 8, \
                kwv + ((tt) % 3) * 1024 + 512); } while (0)
#define STAGE_V(c) do { \
    gload_lds16(vtb + (size_t)(wv * 8 + vlr) * 1024 + (c) * 128 + vu1 * 8, \
                &sm.Vb[(c) % 3][wv * 8][0]); \
    gload_lds16(vtb + (size_t)(wv * 8 + 4 + vlr) * 1024 + (c) * 128 + vu2 * 8, \
                &sm.Vb[(c) % 3][wv * 8 + 4][0]); } while (0)

  f32x4 sc[16];
#pragma unroll
  for (int i = 0; i < 16; ++i) sc[i] = {0.f, 0.f, 0.f, 0.f};

  // ---- QK^T: per-wave ring, NO barriers, self-paced counted vmcnt ----
  STAGE_K(0); STAGE_K(1);
  SB();
#pragma unroll
  for (int tt = 0; tt < 16; ++tt) {
    waitv(tt <= 14 ? 2 : 0);
    SB();
    if (tt + 2 < 16) STAGE_K(tt + 2);
    SB();
    const unsigned short* ksl = kwv + (tt % 3) * 1024 + ln * 64;
    bf16x8 kf0 = *(const bf16x8*)(ksl + (g ^ (ln & 7)) * 8);
    bf16x8 kf1 = *(const bf16x8*)(ksl + ((4 + g) ^ (ln & 7)) * 8);
    PRIO1();
    sc[tt] = __builtin_amdgcn_mfma_f32_16x16x32_bf16(kf0, qf[0], sc[tt], 0, 0, 0);
    sc[tt] = __builtin_amdgcn_mfma_f32_16x16x32_bf16(kf1, qf[1], sc[tt], 0, 0, 0);
    PRIO0();
  }

  // ---- mask loads (in flight while V stages issue / softmax starts) ----
  unsigned mw[16];
  {
    const unsigned char* mrow =
        masks + ((size_t)b * 1024 + m0 + wm * 16 + ln) * 1024 + wq * 16 + g * 4;
#pragma unroll
    for (int tt = 0; tt < 16; ++tt) mw[tt] = *(const unsigned*)(mrow + tt * 64);
  }
  SB();

  LBAR();                       // all waves past QK; K regions reusable for V
  STAGE_V(0); STAGE_V(1);       // V latency hides under softmax
  SB();

  // ---- softmax, ONE barrier (rows lane-local: q-row = ln) ----
  // max is invariant to the positive 1/sqrt(64) scale; fold it into exp2.
  const float C = 0.18033688011112042f;   // 0.125 * log2(e)
  float mx = -3.0e30f;
#pragma unroll
  for (int tt = 0; tt < 16; ++tt) {
    if (mw[tt]) {
#pragma unroll
      for (int r = 0; r < 4; ++r)
        if ((mw[tt] >> (8 * r)) & 0xffu) sc[tt][r] = -1.0e30f;
    }
#pragma unroll
    for (int r = 0; r < 4; ++r) mx = fmaxf(mx, sc[tt][r]);
  }
  mx = fmaxf(mx, __shfl_xor(mx, 16));
  mx = fmaxf(mx, __shfl_xor(mx, 32));     // mx = this wave's row max
  const float mtl = mx * C;
  float sum = 0.f;                        // partial sum with LOCAL max
#pragma unroll
  for (int tt = 0; tt < 16; ++tt)
#pragma unroll
    for (int r = 0; r < 4; ++r)
      sum += exp2f(__builtin_fmaf(sc[tt][r], C, -mtl));
  sum += __shfl_xor(sum, 16);
  sum += __shfl_xor(sum, 32);
  if (g == 0) { red[0][wm][ln][wq] = mx; red[1][wm][ln][wq] = sum; }
  LBAR();
  float m4 = fmaxf(fmaxf(red[0][wm][ln][0], red[0][wm][ln][1]),
                   fmaxf(red[0][wm][ln][2], red[0][wm][ln][3]));
  float l4 = 0.f;
#pragma unroll
  for (int i = 0; i < 4; ++i)
    l4 += red[1][wm][ln][i] * exp2f((red[0][wm][ln][i] - m4) * C);
  // P = exp2(s*C + beta), beta folds global max AND normalization
  const float beta = __builtin_fmaf(-m4, C, -__builtin_log2f(l4));

  // ---- normalized bf16 P fragments (also the attention output values) ----
  bf16x8 af8[8];
#pragma unroll
  for (int c = 0; c < 8; ++c) {
    bf16x8 a;
#pragma unroll
    for (int r = 0; r < 4; ++r)
      a[r] = (short)f2bf(exp2f(__builtin_fmaf(sc[2 * c][r], C, beta)));
#pragma unroll
    for (int r = 0; r < 4; ++r)
      a[4 + r] = (short)f2bf(exp2f(__builtin_fmaf(sc[2 * c + 1][r], C, beta)));
    af8[c] = a;
  }

  // ---- PV + interleaved attention stores ----
  // issue order/iter: [waitv][BAR][STAGE_V(c+2)][4 MFMA][2 stores]
  // in-order vmcnt: younger-than-V(c) = {2,4,6,6,6,6,6,4} for c=0..7
  f32x4 cacc[4];
#pragma unroll
  for (int i = 0; i < 4; ++i) cacc[i] = {0.f, 0.f, 0.f, 0.f};
  const size_t abase =
      ((size_t)(b * 16 + h) * 1024 + (m0 + wm * 16 + ln)) * 1024 + wq * 16 + g * 4;
#pragma unroll
  for (int c = 0; c < 8; ++c) {
    waitv(c == 0 ? 2 : (c == 1 ? 4 : (c <= 6 ? 6 : 4)));
    BAR();
    if (c + 2 < 8) STAGE_V(c + 2);
    SB();
#pragma unroll
    for (int ni = 0; ni < 4; ++ni) {
      const int d = ni * 16 + ln;
      const int u0 = (2 * wq + (g >> 1)) ^ (ln & 7);
      const int u1 = (8 + 2 * wq + (g >> 1)) ^ (ln & 7);
      bf16x4 b0 = *(const bf16x4*)&sm.Vb[c % 3][d][u0 * 8 + (g & 1) * 4];
      bf16x4 b1 = *(const bf16x4*)&sm.Vb[c % 3][d][u1 * 8 + (g & 1) * 4];
      bf16x8 bfr = { b0[0], b0[1], b0[2], b0[3], b1[0], b1[1], b1[2], b1[3] };
      PRIO1();
      cacc[ni] = __builtin_amdgcn_mfma_f32_16x16x32_bf16(af8[c], bfr, cacc[ni], 0, 0, 0);
      PRIO0();
    }
    SB();
#pragma unroll
    for (int hf = 0; hf < 2; ++hf) {
      f32x4 v = { bf2f((unsigned short)af8[c][hf * 4 + 0]),
                  bf2f((unsigned short)af8[c][hf * 4 + 1]),
                  bf2f((unsigned short)af8[c][hf * 4 + 2]),
                  bf2f((unsigned short)af8[c][hf * 4 + 3]) };
      *(f32x4*)(attn_out + abase + (2 * c + hf) * 64) = v;
    }
    SB();
  }

  // ---- cross-wave ctx reduction + residual -> d_out ----
  LBAR();                       // all Vb reads done; reuse as ctxp
#pragma unroll
  for (int ni = 0; ni < 4; ++ni)
#pragma unroll
    for (int r = 0; r < 4; ++r)
      sm.ctxp[wq][wm * 16 + g * 4 + r][ni * 16 + ln] = cacc[ni][r];
  LBAR();
  {
    const int m = t >> 4, d4 = (t & 15) * 4;
    f32x4 s0 = *(const f32x4*)&sm.ctxp[0][m][d4];
    f32x4 s1 = *(const f32x4*)&sm.ctxp[1][m][d4];
    f32x4 s2 = *(const f32x4*)&sm.ctxp[2][m][d4];
    f32x4 s3 = *(const f32x4*)&sm.ctxp[3][m][d4];
    f32x4 s = s0 + s1 + s2 + s3;
    const unsigned short* qrow = qp + (rowbase + m) * 1024 + h * 64 + d4;
    u16x4 qv = *(const u16x4*)qrow;
    f32x4 qf32 = { bf2f(qv[0]), bf2f(qv[1]), bf2f(qv[2]), bf2f(qv[3]) };
    s = s + qf32;
    *(f32x4*)(res_out + (rowbase + m) * 1024 + h * 64 + d4) = s;
  }
#undef STAGE_K
#undef STAGE_V
}

// ---------------------------------------------------------------------------
// In-place LayerNorm on d_out[:B*L*D]: out = LN(out) * g + b, one block/row.
// ---------------------------------------------------------------------------
__global__ __launch_bounds__(256) void ln_kernel(
    float* __restrict__ io,
    const float* __restrict__ gma, const float* __restrict__ bta)
{
  __shared__ float rbuf[2][4];
  const int r = blockIdx.x, t = threadIdx.x;
  const int i4 = t * 4;
  const size_t base = (size_t)r * 1024 + i4;
  f32x4 x = *(const f32x4*)(io + base);
  float s = x[0] + x[1] + x[2] + x[3];
  float q = x[0]*x[0] + x[1]*x[1] + x[2]*x[2] + x[3]*x[3];
#pragma unroll
  for (int off = 1; off < 64; off <<= 1) {
    s += __shfl_xor(s, off);
    q += __shfl_xor(q, off);
  }
  const int wv = t >> 6;
  if ((t & 63) == 0) { rbuf[0][wv] = s; rbuf[1][wv] = q; }
  __syncthreads();
  s = rbuf[0][0] + rbuf[0][1] + rbuf[0][2] + rbuf[0][3];
  q = rbuf[1][0] + rbuf[1][1] + rbuf[1][2] + rbuf[1][3];
  float mu = s * (1.0f / 1024.0f);
  float var = q * (1.0f / 1024.0f) - mu * mu;
  float is = rsqrtf(var + 1e-6f);
  f32x4 gv = *(const f32x4*)(gma + i4);
  f32x4 bv = *(const f32x4*)(bta + i4);
  f32x4 o;
#pragma unroll
  for (int k = 0; k < 4; ++k) o[k] = (x[k] - mu) * is * gv[k] + bv[k];
  *(f32x4*)(io + base) = o;
}

// ---------------------------------------------------------------------------
extern "C" void kernel_launch(void* const* d_in, const int* in_sizes, int n_in,
                              void* d_out, int out_size, void* d_ws, size_t ws_size,
                              hipStream_t stream) {
  const float* q  = (const float*)d_in[0];
  const float* k  = (const float*)d_in[1];
  const float* v  = (const float*)d_in[2];
  const unsigned char* masks = (const unsigned char*)d_in[3];
  const float* Wq = (const float*)d_in[4];
  const float* bq = (const float*)d_in[5];
  const float* Wk = (const float*)d_in[6];
  const float* bk = (const float*)d_in[7];
  const float* Wv = (const float*)d_in[8];
  const float* bv = (const float*)d_in[9];
  const float* lg = (const float*)d_in[10];
  const float* lb = (const float*)d_in[11];

  float* out = (float*)d_out;
  float* attn_out = out + (size_t)4 * 1024 * 1024;

  // workspace: 24 MB (qp | kp | vt, all bf16 4M elems each)
  unsigned short* qp = (unsigned short*)d_ws;
  unsigned short* kp = qp + 4194304;
  unsigned short* vt = kp + 4194304;

  hipLaunchKernelGGL(gemm_kernel, dim3(768), dim3(512), 0, stream,
                     q, k, v, Wq, Wk, Wv, bq, bk, bv, qp, kp, vt);
  hipLaunchKernelGGL(attn_kernel, dim3(2048), dim3(512), 0, stream,
                     qp, kp, vt, masks, attn_out, out);
  hipLaunchKernelGGL(ln_kernel, dim3(4096), dim3(256), 0, stream,
                     out, lg, lb);
}

// Round 9
// 177.269 us; speedup vs baseline: 1.1640x; 1.1640x over previous
//
#include <hip/hip_runtime.h>
#include <hip/hip_bf16.h>

typedef short bf16x8 __attribute__((ext_vector_type(8)));
typedef short bf16x4 __attribute__((ext_vector_type(4)));
typedef float f32x4 __attribute__((ext_vector_type(4)));
typedef unsigned short u16x8 __attribute__((ext_vector_type(8)));
typedef unsigned short u16x4 __attribute__((ext_vector_type(4)));

#define DEV static __device__ __forceinline__

DEV unsigned short f2bf(float f) {
  unsigned int u = __builtin_bit_cast(unsigned int, f);
  u += 0x7FFFu + ((u >> 16) & 1u);   // round-to-nearest-even
  return (unsigned short)(u >> 16);
}
DEV float bf2f(unsigned short u) {
  return __builtin_bit_cast(float, (unsigned int)u << 16);
}

DEV void gload_lds16(const unsigned short* g, unsigned short* l) {
  __builtin_amdgcn_global_load_lds(
      (const __attribute__((address_space(1))) unsigned int*)g,
      (__attribute__((address_space(3))) unsigned int*)l, 16, 0, 0);
}

DEV void waitv(int n) {   // n is compile-time under full unroll -> folds
  switch (n) {
    case 0: asm volatile("s_waitcnt vmcnt(0)" ::: "memory"); break;
    case 1: asm volatile("s_waitcnt vmcnt(1)" ::: "memory"); break;
    case 2: asm volatile("s_waitcnt vmcnt(2)" ::: "memory"); break;
    case 4: asm volatile("s_waitcnt vmcnt(4)" ::: "memory"); break;
    case 6: asm volatile("s_waitcnt vmcnt(6)" ::: "memory"); break;
    default: asm volatile("s_waitcnt vmcnt(0)" ::: "memory"); break;
  }
}

#define SB() __builtin_amdgcn_sched_barrier(0)
#define BAR() do { __builtin_amdgcn_s_barrier(); SB(); } while (0)
#define LBAR() do { asm volatile("s_waitcnt lgkmcnt(0)" ::: "memory"); \
                    SB(); \
                    __builtin_amdgcn_s_barrier(); \
                    SB(); } while (0)
#define PRIO1() __builtin_amdgcn_s_setprio(1)
#define PRIO0() __builtin_amdgcn_s_setprio(0)

// ---------------------------------------------------------------------------
// Convert pass: f32 -> bf16 for q,k,v (4M elems each) and Wq,Wk,Wv (1M each).
// ---------------------------------------------------------------------------
__global__ __launch_bounds__(256) void cvt_kernel(
    const float* __restrict__ q, const float* __restrict__ k,
    const float* __restrict__ v, const float* __restrict__ wq,
    const float* __restrict__ wk, const float* __restrict__ wv,
    unsigned short* __restrict__ xq, unsigned short* __restrict__ xk,
    unsigned short* __restrict__ xv, unsigned short* __restrict__ wqb,
    unsigned short* __restrict__ wkb, unsigned short* __restrict__ wvb)
{
  int tid = blockIdx.x * 256 + threadIdx.x;
  const float* src; unsigned short* dst; int off;
  if      (tid <  524288) { src = q;  dst = xq;  off = tid; }
  else if (tid < 1048576) { src = k;  dst = xk;  off = tid -  524288; }
  else if (tid < 1572864) { src = v;  dst = xv;  off = tid - 1048576; }
  else if (tid < 1703936) { src = wq; dst = wqb; off = tid - 1572864; }
  else if (tid < 1835008) { src = wk; dst = wkb; off = tid - 1703936; }
  else                    { src = wv; dst = wvb; off = tid - 1835008; }
  size_t e = (size_t)off * 8;
  float4 a = *(const float4*)(src + e);
  float4 b = *(const float4*)(src + e + 4);
  u16x8 p = { f2bf(a.x), f2bf(a.y), f2bf(a.z), f2bf(a.w),
              f2bf(b.x), f2bf(b.y), f2bf(b.z), f2bf(b.w) };
  *(u16x8*)(dst + e) = p;
}

// ---------------------------------------------------------------------------
// Fused projection GEMMs: seg = blockIdx>>8 picks (X, W, bias, out, mode).
// C[4096][1024] = X @ W^T + bias, bf16 in/out. 128x128 tile, BK=64,
// 512 threads (8 waves, 2m x 4n). global_load_lds staging with 2-slot
// double buffer (stage kt+1 before MFMA of kt; vmcnt(0)+barrier per kt).
// Both-sides XOR swizzle: DMA source unit (lane&7)^lrow (linear LDS dest),
// fragment read unit (ks*4+g)^(ln&7) -> kills the 16-way bank conflict.
// XCD swizzle: 8 n-blocks of one m-panel share an XCD (A panel L2-hits).
// mode 0: bf16 row-major. mode 2: bf16 transposed per-head (V).
// ---------------------------------------------------------------------------
__global__ __launch_bounds__(512, 2) void gemm_kernel(
    const unsigned short* __restrict__ xq, const unsigned short* __restrict__ xk,
    const unsigned short* __restrict__ xv, const unsigned short* __restrict__ wqb,
    const unsigned short* __restrict__ wkb, const unsigned short* __restrict__ wvb,
    const float* __restrict__ bq, const float* __restrict__ bk,
    const float* __restrict__ bv, unsigned short* __restrict__ qp,
    unsigned short* __restrict__ kp, unsigned short* __restrict__ vt)
{
  __shared__ union {
    unsigned short ab[2][2][128][64];   // [buf][A=0/B=1][row][unit*8]
    unsigned short T[128][132];         // V-transpose epilogue (+4 pad)
  } smu;
  const int t = threadIdx.x, lane = t & 63, wv8 = t >> 6;
  const int ln = lane & 15, g = lane >> 4;
  const int wm2 = wv8 >> 2, wn4 = wv8 & 3;
  const int seg = blockIdx.x >> 8, lb = blockIdx.x & 255;
  const int x8 = lb & 7, s32 = lb >> 3;
  const int m0 = (x8 * 4 + (s32 >> 3)) * 128;   // same-m blocks share an XCD
  const int n0 = (s32 & 7) * 128;

  const unsigned short* X; const unsigned short* W; const float* bias;
  unsigned short* outR; int mode;
  if (seg == 0)      { X = xq; W = wqb; bias = bq; outR = qp; mode = 0; }
  else if (seg == 1) { X = xk; W = wkb; bias = bk; outR = kp; mode = 0; }
  else               { X = xv; W = wvb; bias = bv; outR = vt; mode = 2; }

  f32x4 acc[4][2];
#pragma unroll
  for (int i = 0; i < 4; ++i)
#pragma unroll
    for (int j = 0; j < 2; ++j) acc[i][j] = {0.f, 0.f, 0.f, 0.f};

  const int lrow = lane >> 3;                     // 0..7
  const int lcol = ((lane & 7) ^ lrow) * 8;       // pre-swizzled source unit

#define STAGE_G(kt) do { \
    const int _k0 = (kt) * 64; \
    _Pragma("unroll") \
    for (int i = 0; i < 2; ++i) { \
      const int r = wv8 * 16 + i * 8; \
      gload_lds16(X + (size_t)(m0 + r + lrow) * 1024 + _k0 + lcol, \
                  &smu.ab[(kt) & 1][0][r][0]); \
      gload_lds16(W + (size_t)(n0 + r + lrow) * 1024 + _k0 + lcol, \
                  &smu.ab[(kt) & 1][1][r][0]); \
    } } while (0)

  STAGE_G(0);
  waitv(0);
  BAR();
#pragma unroll 2
  for (int kt = 0; kt < 16; ++kt) {
    if (kt < 15) STAGE_G(kt + 1);
    SB();
#pragma unroll
    for (int ks = 0; ks < 2; ++ks) {
      bf16x8 af[4], bfr[2];
      const int ru = ((ks * 4 + g) ^ (ln & 7)) * 8;   // swizzled read unit
#pragma unroll
      for (int i = 0; i < 4; ++i)
        af[i] = *(const bf16x8*)&smu.ab[kt & 1][0][wm2 * 64 + i * 16 + ln][ru];
#pragma unroll
      for (int j = 0; j < 2; ++j)
        bfr[j] = *(const bf16x8*)&smu.ab[kt & 1][1][wn4 * 32 + j * 16 + ln][ru];
      PRIO1();
#pragma unroll
      for (int i = 0; i < 4; ++i)
#pragma unroll
        for (int j = 0; j < 2; ++j)
          acc[i][j] = __builtin_amdgcn_mfma_f32_16x16x32_bf16(
              af[i], bfr[j], acc[i][j], 0, 0, 0);
      PRIO0();
    }
    SB();
    waitv(0);            // next-tile DMAs landed (partially hidden by MFMA)
    BAR();
  }

  float bvv[2];
#pragma unroll
  for (int j = 0; j < 2; ++j) bvv[j] = bias[n0 + wn4 * 32 + j * 16 + ln];

  if (mode == 0) {
#pragma unroll
    for (int i = 0; i < 4; ++i)
#pragma unroll
      for (int j = 0; j < 2; ++j)
#pragma unroll
        for (int r = 0; r < 4; ++r) {
          int row = m0 + wm2 * 64 + i * 16 + g * 4 + r;
          int col = n0 + wn4 * 32 + j * 16 + ln;
          outR[(size_t)row * 1024 + col] = f2bf(acc[i][j][r] + bvv[j]);
        }
  } else {
    __syncthreads();   // all fragment reads done; reuse LDS as T
#pragma unroll
    for (int i = 0; i < 4; ++i)
#pragma unroll
      for (int j = 0; j < 2; ++j)
#pragma unroll
        for (int r = 0; r < 4; ++r)
          smu.T[wn4 * 32 + j * 16 + ln][wm2 * 64 + i * 16 + g * 4 + r] =
              f2bf(acc[i][j][r] + bvv[j]);
    __syncthreads();
    const int bb = m0 >> 10, l0 = m0 & 1023;
#pragma unroll
    for (int it = 0; it < 4; ++it) {
      const int col = it * 32 + (t >> 4);
      const int r8 = (t & 15) * 8;
      *(u16x8*)&outR[((size_t)(bb * 16 + (n0 >> 6) + (col >> 6)) * 64 + (col & 63)) * 1024 + l0 + r8] =
          *(const u16x8*)&smu.T[col][r8];
    }
  }
#undef STAGE_G
}

// ---------------------------------------------------------------------------
// Attention (unchanged from round 8): block = (b, h, 32 q-rows), 8 waves.
// S^T = K*Q^T. QK: per-wave private K rings, zero barriers, self-paced
// counted vmcnt. Softmax: ONE barrier (local-max partial sums, normalization
// folded into exponent). PV: shared 3-slot V ring, 1 barrier/chunk, counted
// vmcnt, attention stores interleaved. setprio around MFMA clusters.
// ---------------------------------------------------------------------------
__global__ __launch_bounds__(512, 2) void attn_kernel(
    const unsigned short* __restrict__ qp, const unsigned short* __restrict__ kp,
    const unsigned short* __restrict__ vt, const unsigned char* __restrict__ masks,
    float* __restrict__ attn_out, float* __restrict__ res_out)
{
  __shared__ union {
    unsigned short Kw[8][3][1024];   // per-wave K rings: [wave][slot][16*64]
    unsigned short Vb[3][64][128];   // shared V ring
    float ctxp[4][32][68];           // reduction phase (+4 pad: bank spread)
  } sm;
  __shared__ float red[2][2][16][4]; // [max/sum][wm][ln][wq]

  const int t = threadIdx.x;
  const int wv = t >> 6, lane = t & 63;
  const int ln = lane & 15, g = lane >> 4;
  const int wq = wv & 3, wm = wv >> 2;
  const int hw = blockIdx.x;
  const int lid = (hw & 7) * 256 + (hw >> 3);  // cluster same-(b,h) per XCD
  const int b = lid >> 9, h = (lid >> 5) & 15, m0 = (lid & 31) * 32;
  const size_t rowbase = (size_t)(b * 1024 + m0);

  // ---- Q fragments (oldest vmcnt entries; retired by the first QK waits) ----
  bf16x8 qf[2];
  {
    const unsigned short* qb =
        qp + (rowbase + wm * 16 + ln) * 1024 + h * 64 + g * 8;
    qf[0] = *(const bf16x8*)qb;
    qf[1] = *(const bf16x8*)(qb + 32);
  }
  SB();

  // staging geometry
  const int slr8 = lane >> 3;                // 0..7 local row (K chunks)
  const int suK = (lane & 7) ^ slr8;         // swizzled K source unit
  const int vlr = lane >> 4;                 // 0..3 local row (V chunks)
  const int vu1 = (lane & 15) ^ vlr;         // V source units (rows +0..3)
  const int vu2 = (lane & 15) ^ (4 + vlr);   //               (rows +4..7)
  const unsigned short* kbase = kp + (size_t)b * 1048576 + h * 64;
  const unsigned short* vtb = vt + ((size_t)(b * 16 + h) * 64) * 1024;
  unsigned short* kwv = &sm.Kw[wv][0][0];

#define STAGE_K(tt) do { \
    gload_lds16(kbase + (size_t)((tt) * 64 + wq * 16 + slr8) * 1024 + suK * 8, \
                kwv + ((tt) % 3) * 1024); \
    gload_lds16(kbase + (size_t)((tt) * 64 + wq * 16 + 8 + slr8) * 1024 + suK * 8, \
                kwv + ((tt) % 3) * 1024 + 512); } while (0)
#define STAGE_V(c) do { \
    gload_lds16(vtb + (size_t)(wv * 8 + vlr) * 1024 + (c) * 128 + vu1 * 8, \
                &sm.Vb[(c) % 3][wv * 8][0]); \
    gload_lds16(vtb + (size_t)(wv * 8 + 4 + vlr) * 1024 + (c) * 128 + vu2 * 8, \
                &sm.Vb[(c) % 3][wv * 8 + 4][0]); } while (0)

  f32x4 sc[16];
#pragma unroll
  for (int i = 0; i < 16; ++i) sc[i] = {0.f, 0.f, 0.f, 0.f};

  // ---- QK^T: per-wave ring, NO barriers, self-paced counted vmcnt ----
  STAGE_K(0); STAGE_K(1);
  SB();
#pragma unroll
  for (int tt = 0; tt < 16; ++tt) {
    waitv(tt <= 14 ? 2 : 0);
    SB();
    if (tt + 2 < 16) STAGE_K(tt + 2);
    SB();
    const unsigned short* ksl = kwv + (tt % 3) * 1024 + ln * 64;
    bf16x8 kf0 = *(const bf16x8*)(ksl + (g ^ (ln & 7)) * 8);
    bf16x8 kf1 = *(const bf16x8*)(ksl + ((4 + g) ^ (ln & 7)) * 8);
    PRIO1();
    sc[tt] = __builtin_amdgcn_mfma_f32_16x16x32_bf16(kf0, qf[0], sc[tt], 0, 0, 0);
    sc[tt] = __builtin_amdgcn_mfma_f32_16x16x32_bf16(kf1, qf[1], sc[tt], 0, 0, 0);
    PRIO0();
  }

  // ---- mask loads (in flight while V stages issue / softmax starts) ----
  unsigned mw[16];
  {
    const unsigned char* mrow =
        masks + ((size_t)b * 1024 + m0 + wm * 16 + ln) * 1024 + wq * 16 + g * 4;
#pragma unroll
    for (int tt = 0; tt < 16; ++tt) mw[tt] = *(const unsigned*)(mrow + tt * 64);
  }
  SB();

  LBAR();                       // all waves past QK; K regions reusable for V
  STAGE_V(0); STAGE_V(1);       // V latency hides under softmax
  SB();

  // ---- softmax, ONE barrier (rows lane-local: q-row = ln) ----
  const float C = 0.18033688011112042f;   // 0.125 * log2(e)
  float mx = -3.0e30f;
#pragma unroll
  for (int tt = 0; tt < 16; ++tt) {
    if (mw[tt]) {
#pragma unroll
      for (int r = 0; r < 4; ++r)
        if ((mw[tt] >> (8 * r)) & 0xffu) sc[tt][r] = -1.0e30f;
    }
#pragma unroll
    for (int r = 0; r < 4; ++r) mx = fmaxf(mx, sc[tt][r]);
  }
  mx = fmaxf(mx, __shfl_xor(mx, 16));
  mx = fmaxf(mx, __shfl_xor(mx, 32));     // mx = this wave's row max
  const float mtl = mx * C;
  float sum = 0.f;                        // partial sum with LOCAL max
#pragma unroll
  for (int tt = 0; tt < 16; ++tt)
#pragma unroll
    for (int r = 0; r < 4; ++r)
      sum += exp2f(__builtin_fmaf(sc[tt][r], C, -mtl));
  sum += __shfl_xor(sum, 16);
  sum += __shfl_xor(sum, 32);
  if (g == 0) { red[0][wm][ln][wq] = mx; red[1][wm][ln][wq] = sum; }
  LBAR();
  float m4 = fmaxf(fmaxf(red[0][wm][ln][0], red[0][wm][ln][1]),
                   fmaxf(red[0][wm][ln][2], red[0][wm][ln][3]));
  float l4 = 0.f;
#pragma unroll
  for (int i = 0; i < 4; ++i)
    l4 += red[1][wm][ln][i] * exp2f((red[0][wm][ln][i] - m4) * C);
  // P = exp2(s*C + beta), beta folds global max AND normalization
  const float beta = __builtin_fmaf(-m4, C, -__builtin_log2f(l4));

  // ---- normalized bf16 P fragments (also the attention output values) ----
  bf16x8 af8[8];
#pragma unroll
  for (int c = 0; c < 8; ++c) {
    bf16x8 a;
#pragma unroll
    for (int r = 0; r < 4; ++r)
      a[r] = (short)f2bf(exp2f(__builtin_fmaf(sc[2 * c][r], C, beta)));
#pragma unroll
    for (int r = 0; r < 4; ++r)
      a[4 + r] = (short)f2bf(exp2f(__builtin_fmaf(sc[2 * c + 1][r], C, beta)));
    af8[c] = a;
  }

  // ---- PV + interleaved attention stores ----
  // issue order/iter: [waitv][BAR][STAGE_V(c+2)][4 MFMA][2 stores]
  // in-order vmcnt: younger-than-V(c) = {2,4,6,6,6,6,6,4} for c=0..7
  f32x4 cacc[4];
#pragma unroll
  for (int i = 0; i < 4; ++i) cacc[i] = {0.f, 0.f, 0.f, 0.f};
  const size_t abase =
      ((size_t)(b * 16 + h) * 1024 + (m0 + wm * 16 + ln)) * 1024 + wq * 16 + g * 4;
#pragma unroll
  for (int c = 0; c < 8; ++c) {
    waitv(c == 0 ? 2 : (c == 1 ? 4 : (c <= 6 ? 6 : 4)));
    BAR();
    if (c + 2 < 8) STAGE_V(c + 2);
    SB();
#pragma unroll
    for (int ni = 0; ni < 4; ++ni) {
      const int d = ni * 16 + ln;
      const int u0 = (2 * wq + (g >> 1)) ^ (ln & 7);
      const int u1 = (8 + 2 * wq + (g >> 1)) ^ (ln & 7);
      bf16x4 b0 = *(const bf16x4*)&sm.Vb[c % 3][d][u0 * 8 + (g & 1) * 4];
      bf16x4 b1 = *(const bf16x4*)&sm.Vb[c % 3][d][u1 * 8 + (g & 1) * 4];
      bf16x8 bfr = { b0[0], b0[1], b0[2], b0[3], b1[0], b1[1], b1[2], b1[3] };
      PRIO1();
      cacc[ni] = __builtin_amdgcn_mfma_f32_16x16x32_bf16(af8[c], bfr, cacc[ni], 0, 0, 0);
      PRIO0();
    }
    SB();
#pragma unroll
    for (int hf = 0; hf < 2; ++hf) {
      f32x4 v = { bf2f((unsigned short)af8[c][hf * 4 + 0]),
                  bf2f((unsigned short)af8[c][hf * 4 + 1]),
                  bf2f((unsigned short)af8[c][hf * 4 + 2]),
                  bf2f((unsigned short)af8[c][hf * 4 + 3]) };
      *(f32x4*)(attn_out + abase + (2 * c + hf) * 64) = v;
    }
    SB();
  }

  // ---- cross-wave ctx reduction + residual -> d_out ----
  LBAR();                       // all Vb reads done; reuse as ctxp
#pragma unroll
  for (int ni = 0; ni < 4; ++ni)
#pragma unroll
    for (int r = 0; r < 4; ++r)
      sm.ctxp[wq][wm * 16 + g * 4 + r][ni * 16 + ln] = cacc[ni][r];
  LBAR();
  {
    const int m = t >> 4, d4 = (t & 15) * 4;
    f32x4 s0 = *(const f32x4*)&sm.ctxp[0][m][d4];
    f32x4 s1 = *(const f32x4*)&sm.ctxp[1][m][d4];
    f32x4 s2 = *(const f32x4*)&sm.ctxp[2][m][d4];
    f32x4 s3 = *(const f32x4*)&sm.ctxp[3][m][d4];
    f32x4 s = s0 + s1 + s2 + s3;
    const unsigned short* qrow = qp + (rowbase + m) * 1024 + h * 64 + d4;
    u16x4 qv = *(const u16x4*)qrow;
    f32x4 qf32 = { bf2f(qv[0]), bf2f(qv[1]), bf2f(qv[2]), bf2f(qv[3]) };
    s = s + qf32;
    *(f32x4*)(res_out + (rowbase + m) * 1024 + h * 64 + d4) = s;
  }
#undef STAGE_K
#undef STAGE_V
}

// ---------------------------------------------------------------------------
// In-place LayerNorm on d_out[:B*L*D]: out = LN(out) * g + b, one block/row.
// ---------------------------------------------------------------------------
__global__ __launch_bounds__(256) void ln_kernel(
    float* __restrict__ io,
    const float* __restrict__ gma, const float* __restrict__ bta)
{
  __shared__ float rbuf[2][4];
  const int r = blockIdx.x, t = threadIdx.x;
  const int i4 = t * 4;
  const size_t base = (size_t)r * 1024 + i4;
  f32x4 x = *(const f32x4*)(io + base);
  float s = x[0] + x[1] + x[2] + x[3];
  float q = x[0]*x[0] + x[1]*x[1] + x[2]*x[2] + x[3]*x[3];
#pragma unroll
  for (int off = 1; off < 64; off <<= 1) {
    s += __shfl_xor(s, off);
    q += __shfl_xor(q, off);
  }
  const int wv = t >> 6;
  if ((t & 63) == 0) { rbuf[0][wv] = s; rbuf[1][wv] = q; }
  __syncthreads();
  s = rbuf[0][0] + rbuf[0][1] + rbuf[0][2] + rbuf[0][3];
  q = rbuf[1][0] + rbuf[1][1] + rbuf[1][2] + rbuf[1][3];
  float mu = s * (1.0f / 1024.0f);
  float var = q * (1.0f / 1024.0f) - mu * mu;
  float is = rsqrtf(var + 1e-6f);
  f32x4 gv = *(const f32x4*)(gma + i4);
  f32x4 bv = *(const f32x4*)(bta + i4);
  f32x4 o;
#pragma unroll
  for (int k = 0; k < 4; ++k) o[k] = (x[k] - mu) * is * gv[k] + bv[k];
  *(f32x4*)(io + base) = o;
}

// ---------------------------------------------------------------------------
extern "C" void kernel_launch(void* const* d_in, const int* in_sizes, int n_in,
                              void* d_out, int out_size, void* d_ws, size_t ws_size,
                              hipStream_t stream) {
  const float* q  = (const float*)d_in[0];
  const float* k  = (const float*)d_in[1];
  const float* v  = (const float*)d_in[2];
  const unsigned char* masks = (const unsigned char*)d_in[3];
  const float* Wq = (const float*)d_in[4];
  const float* bq = (const float*)d_in[5];
  const float* Wk = (const float*)d_in[6];
  const float* bk = (const float*)d_in[7];
  const float* Wv = (const float*)d_in[8];
  const float* bv = (const float*)d_in[9];
  const float* lg = (const float*)d_in[10];
  const float* lb = (const float*)d_in[11];

  float* out = (float*)d_out;
  float* attn_out = out + (size_t)4 * 1024 * 1024;

  // bf16 input scratch lives in the attn region of d_out (overwritten later
  // by attn_kernel -- all reads happen in cvt/gemm, stream-ordered before).
  unsigned short* xq  = (unsigned short*)attn_out;
  unsigned short* xk  = xq + 4194304;
  unsigned short* xv  = xk + 4194304;
  unsigned short* wqb = xv + 4194304;
  unsigned short* wkb = wqb + 1048576;
  unsigned short* wvb = wkb + 1048576;

  // workspace: 24 MB (qp | kp | vt, all bf16 4M elems each)
  unsigned short* qp = (unsigned short*)d_ws;
  unsigned short* kp = qp + 4194304;
  unsigned short* vt = kp + 4194304;

  hipLaunchKernelGGL(cvt_kernel, dim3(7680), dim3(256), 0, stream,
                     q, k, v, Wq, Wk, Wv, xq, xk, xv, wqb, wkb, wvb);
  hipLaunchKernelGGL(gemm_kernel, dim3(768), dim3(512), 0, stream,
                     xq, xk, xv, wqb, wkb, wvb, bq, bk, bv, qp, kp, vt);
  hipLaunchKernelGGL(attn_kernel, dim3(2048), dim3(512), 0, stream,
                     qp, kp, vt, masks, attn_out, out);
  hipLaunchKernelGGL(ln_kernel, dim3(4096), dim3(256), 0, stream,
                     out, lg, lb);
}

// Round 10
// 176.459 us; speedup vs baseline: 1.1694x; 1.0046x over previous
//
#include <hip/hip_runtime.h>
#include <hip/hip_bf16.h>

typedef short bf16x8 __attribute__((ext_vector_type(8)));
typedef short bf16x4 __attribute__((ext_vector_type(4)));
typedef float f32x4 __attribute__((ext_vector_type(4)));
typedef unsigned short u16x8 __attribute__((ext_vector_type(8)));
typedef unsigned short u16x4 __attribute__((ext_vector_type(4)));

#define DEV static __device__ __forceinline__

DEV unsigned short f2bf(float f) {
  unsigned int u = __builtin_bit_cast(unsigned int, f);
  u += 0x7FFFu + ((u >> 16) & 1u);   // round-to-nearest-even
  return (unsigned short)(u >> 16);
}
DEV float bf2f(unsigned short u) {
  return __builtin_bit_cast(float, (unsigned int)u << 16);
}

DEV void gload_lds16(const unsigned short* g, unsigned short* l) {
  __builtin_amdgcn_global_load_lds(
      (const __attribute__((address_space(1))) unsigned int*)g,
      (__attribute__((address_space(3))) unsigned int*)l, 16, 0, 0);
}

DEV void waitv(int n) {   // n is compile-time under full unroll -> folds
  switch (n) {
    case 0: asm volatile("s_waitcnt vmcnt(0)" ::: "memory"); break;
    case 1: asm volatile("s_waitcnt vmcnt(1)" ::: "memory"); break;
    case 2: asm volatile("s_waitcnt vmcnt(2)" ::: "memory"); break;
    case 4: asm volatile("s_waitcnt vmcnt(4)" ::: "memory"); break;
    case 6: asm volatile("s_waitcnt vmcnt(6)" ::: "memory"); break;
    default: asm volatile("s_waitcnt vmcnt(0)" ::: "memory"); break;
  }
}

#define SB() __builtin_amdgcn_sched_barrier(0)
#define BAR() do { __builtin_amdgcn_s_barrier(); SB(); } while (0)
#define LBAR() do { asm volatile("s_waitcnt lgkmcnt(0)" ::: "memory"); \
                    SB(); \
                    __builtin_amdgcn_s_barrier(); \
                    SB(); } while (0)
#define WAITL() do { asm volatile("s_waitcnt lgkmcnt(0)" ::: "memory"); SB(); } while (0)
#define PRIO1() __builtin_amdgcn_s_setprio(1)
#define PRIO0() __builtin_amdgcn_s_setprio(0)

// ---------------------------------------------------------------------------
// Convert pass: f32 -> bf16 for q,k,v (4M elems each) and Wq,Wk,Wv (1M each).
// ---------------------------------------------------------------------------
__global__ __launch_bounds__(256) void cvt_kernel(
    const float* __restrict__ q, const float* __restrict__ k,
    const float* __restrict__ v, const float* __restrict__ wq,
    const float* __restrict__ wk, const float* __restrict__ wv,
    unsigned short* __restrict__ xq, unsigned short* __restrict__ xk,
    unsigned short* __restrict__ xv, unsigned short* __restrict__ wqb,
    unsigned short* __restrict__ wkb, unsigned short* __restrict__ wvb)
{
  int tid = blockIdx.x * 256 + threadIdx.x;
  const float* src; unsigned short* dst; int off;
  if      (tid <  524288) { src = q;  dst = xq;  off = tid; }
  else if (tid < 1048576) { src = k;  dst = xk;  off = tid -  524288; }
  else if (tid < 1572864) { src = v;  dst = xv;  off = tid - 1048576; }
  else if (tid < 1703936) { src = wq; dst = wqb; off = tid - 1572864; }
  else if (tid < 1835008) { src = wk; dst = wkb; off = tid - 1703936; }
  else                    { src = wv; dst = wvb; off = tid - 1835008; }
  size_t e = (size_t)off * 8;
  float4 a = *(const float4*)(src + e);
  float4 b = *(const float4*)(src + e + 4);
  u16x8 p = { f2bf(a.x), f2bf(a.y), f2bf(a.z), f2bf(a.w),
              f2bf(b.x), f2bf(b.y), f2bf(b.z), f2bf(b.w) };
  *(u16x8*)(dst + e) = p;
}

// ---------------------------------------------------------------------------
// Fused projection GEMMs (unchanged from r9): 128x128 tile, BK=64, 8 waves,
// global_load_lds 2-slot double buffer, both-sides XOR swizzle, XCD swizzle.
// ---------------------------------------------------------------------------
__global__ __launch_bounds__(512, 2) void gemm_kernel(
    const unsigned short* __restrict__ xq, const unsigned short* __restrict__ xk,
    const unsigned short* __restrict__ xv, const unsigned short* __restrict__ wqb,
    const unsigned short* __restrict__ wkb, const unsigned short* __restrict__ wvb,
    const float* __restrict__ bq, const float* __restrict__ bk,
    const float* __restrict__ bv, unsigned short* __restrict__ qp,
    unsigned short* __restrict__ kp, unsigned short* __restrict__ vt)
{
  __shared__ union {
    unsigned short ab[2][2][128][64];   // [buf][A=0/B=1][row][unit*8]
    unsigned short T[128][132];         // V-transpose epilogue (+4 pad)
  } smu;
  const int t = threadIdx.x, lane = t & 63, wv8 = t >> 6;
  const int ln = lane & 15, g = lane >> 4;
  const int wm2 = wv8 >> 2, wn4 = wv8 & 3;
  const int seg = blockIdx.x >> 8, lb = blockIdx.x & 255;
  const int x8 = lb & 7, s32 = lb >> 3;
  const int m0 = (x8 * 4 + (s32 >> 3)) * 128;   // same-m blocks share an XCD
  const int n0 = (s32 & 7) * 128;

  const unsigned short* X; const unsigned short* W; const float* bias;
  unsigned short* outR; int mode;
  if (seg == 0)      { X = xq; W = wqb; bias = bq; outR = qp; mode = 0; }
  else if (seg == 1) { X = xk; W = wkb; bias = bk; outR = kp; mode = 0; }
  else               { X = xv; W = wvb; bias = bv; outR = vt; mode = 2; }

  f32x4 acc[4][2];
#pragma unroll
  for (int i = 0; i < 4; ++i)
#pragma unroll
    for (int j = 0; j < 2; ++j) acc[i][j] = {0.f, 0.f, 0.f, 0.f};

  const int lrow = lane >> 3;                     // 0..7
  const int lcol = ((lane & 7) ^ lrow) * 8;       // pre-swizzled source unit

#define STAGE_G(kt) do { \
    const int _k0 = (kt) * 64; \
    _Pragma("unroll") \
    for (int i = 0; i < 2; ++i) { \
      const int r = wv8 * 16 + i * 8; \
      gload_lds16(X + (size_t)(m0 + r + lrow) * 1024 + _k0 + lcol, \
                  &smu.ab[(kt) & 1][0][r][0]); \
      gload_lds16(W + (size_t)(n0 + r + lrow) * 1024 + _k0 + lcol, \
                  &smu.ab[(kt) & 1][1][r][0]); \
    } } while (0)

  STAGE_G(0);
  waitv(0);
  BAR();
#pragma unroll 2
  for (int kt = 0; kt < 16; ++kt) {
    if (kt < 15) STAGE_G(kt + 1);
    SB();
#pragma unroll
    for (int ks = 0; ks < 2; ++ks) {
      bf16x8 af[4], bfr[2];
      const int ru = ((ks * 4 + g) ^ (ln & 7)) * 8;   // swizzled read unit
#pragma unroll
      for (int i = 0; i < 4; ++i)
        af[i] = *(const bf16x8*)&smu.ab[kt & 1][0][wm2 * 64 + i * 16 + ln][ru];
#pragma unroll
      for (int j = 0; j < 2; ++j)
        bfr[j] = *(const bf16x8*)&smu.ab[kt & 1][1][wn4 * 32 + j * 16 + ln][ru];
      PRIO1();
#pragma unroll
      for (int i = 0; i < 4; ++i)
#pragma unroll
        for (int j = 0; j < 2; ++j)
          acc[i][j] = __builtin_amdgcn_mfma_f32_16x16x32_bf16(
              af[i], bfr[j], acc[i][j], 0, 0, 0);
      PRIO0();
    }
    SB();
    waitv(0);            // next-tile DMAs landed (partially hidden by MFMA)
    BAR();
  }

  float bvv[2];
#pragma unroll
  for (int j = 0; j < 2; ++j) bvv[j] = bias[n0 + wn4 * 32 + j * 16 + ln];

  if (mode == 0) {
#pragma unroll
    for (int i = 0; i < 4; ++i)
#pragma unroll
      for (int j = 0; j < 2; ++j)
#pragma unroll
        for (int r = 0; r < 4; ++r) {
          int row = m0 + wm2 * 64 + i * 16 + g * 4 + r;
          int col = n0 + wn4 * 32 + j * 16 + ln;
          outR[(size_t)row * 1024 + col] = f2bf(acc[i][j][r] + bvv[j]);
        }
  } else {
    __syncthreads();   // all fragment reads done; reuse LDS as T
#pragma unroll
    for (int i = 0; i < 4; ++i)
#pragma unroll
      for (int j = 0; j < 2; ++j)
#pragma unroll
        for (int r = 0; r < 4; ++r)
          smu.T[wn4 * 32 + j * 16 + ln][wm2 * 64 + i * 16 + g * 4 + r] =
              f2bf(acc[i][j][r] + bvv[j]);
    __syncthreads();
    const int bb = m0 >> 10, l0 = m0 & 1023;
#pragma unroll
    for (int it = 0; it < 4; ++it) {
      const int col = it * 32 + (t >> 4);
      const int r8 = (t & 15) * 8;
      *(u16x8*)&outR[((size_t)(bb * 16 + (n0 >> 6) + (col >> 6)) * 64 + (col & 63)) * 1024 + l0 + r8] =
          *(const u16x8*)&smu.T[col][r8];
    }
  }
#undef STAGE_G
}

// ---------------------------------------------------------------------------
// Attention: block = (b, h, 32 q-rows), 8 waves. S^T = K*Q^T.
// QK: per-wave private K rings, zero barriers, TRUE DEPTH-3 pipeline —
// prologue stages chunks 0..2; each iter: waitv(4) -> ds_read fragments ->
// lgkmcnt(0) -> stage chunk tt+3 into the freed slot -> MFMA.
// Softmax: ONE barrier. PV: shared 3-slot V ring, depth 2, counted vmcnt,
// attention stores interleaved (verified counts). setprio around MFMA.
// ---------------------------------------------------------------------------
__global__ __launch_bounds__(512, 2) void attn_kernel(
    const unsigned short* __restrict__ qp, const unsigned short* __restrict__ kp,
    const unsigned short* __restrict__ vt, const unsigned char* __restrict__ masks,
    float* __restrict__ attn_out, float* __restrict__ res_out)
{
  __shared__ union {
    unsigned short Kw[8][3][1024];   // per-wave K rings: [wave][slot][16*64]
    unsigned short Vb[3][64][128];   // shared V ring
    float ctxp[4][32][68];           // reduction phase (+4 pad: bank spread)
  } sm;
  __shared__ float red[2][2][16][4]; // [max/sum][wm][ln][wq]

  const int t = threadIdx.x;
  const int wv = t >> 6, lane = t & 63;
  const int ln = lane & 15, g = lane >> 4;
  const int wq = wv & 3, wm = wv >> 2;
  const int hw = blockIdx.x;
  const int lid = (hw & 7) * 256 + (hw >> 3);  // cluster same-(b,h) per XCD
  const int b = lid >> 9, h = (lid >> 5) & 15, m0 = (lid & 31) * 32;
  const size_t rowbase = (size_t)(b * 1024 + m0);

  // ---- Q fragments (oldest vmcnt entries; retired by the first QK wait) ----
  bf16x8 qf[2];
  {
    const unsigned short* qb =
        qp + (rowbase + wm * 16 + ln) * 1024 + h * 64 + g * 8;
    qf[0] = *(const bf16x8*)qb;
    qf[1] = *(const bf16x8*)(qb + 32);
  }
  SB();

  // staging geometry
  const int slr8 = lane >> 3;                // 0..7 local row (K chunks)
  const int suK = (lane & 7) ^ slr8;         // swizzled K source unit
  const int vlr = lane >> 4;                 // 0..3 local row (V chunks)
  const int vu1 = (lane & 15) ^ vlr;         // V source units (rows +0..3)
  const int vu2 = (lane & 15) ^ (4 + vlr);   //               (rows +4..7)
  const unsigned short* kbase = kp + (size_t)b * 1048576 + h * 64;
  const unsigned short* vtb = vt + ((size_t)(b * 16 + h) * 64) * 1024;
  unsigned short* kwv = &sm.Kw[wv][0][0];

#define STAGE_K(tt) do { \
    gload_lds16(kbase + (size_t)((tt) * 64 + wq * 16 + slr8) * 1024 + suK * 8, \
                kwv + ((tt) % 3) * 1024); \
    gload_lds16(kbase + (size_t)((tt) * 64 + wq * 16 + 8 + slr8) * 1024 + suK * 8, \
                kwv + ((tt) % 3) * 1024 + 512); } while (0)
#define STAGE_V(c) do { \
    gload_lds16(vtb + (size_t)(wv * 8 + vlr) * 1024 + (c) * 128 + vu1 * 8, \
                &sm.Vb[(c) % 3][wv * 8][0]); \
    gload_lds16(vtb + (size_t)(wv * 8 + 4 + vlr) * 1024 + (c) * 128 + vu2 * 8, \
                &sm.Vb[(c) % 3][wv * 8 + 4][0]); } while (0)

  f32x4 sc[16];
#pragma unroll
  for (int i = 0; i < 16; ++i) sc[i] = {0.f, 0.f, 0.f, 0.f};

  // ---- QK^T: per-wave ring, NO barriers, depth-3 self-paced pipeline ----
  STAGE_K(0); STAGE_K(1); STAGE_K(2);
  SB();
#pragma unroll
  for (int tt = 0; tt < 16; ++tt) {
    // chunks tt+1, tt+2 stay in flight (4 ops); chunk tt has landed.
    waitv(tt <= 13 ? 4 : (tt == 14 ? 2 : 0));
    SB();
    const unsigned short* ksl = kwv + (tt % 3) * 1024 + ln * 64;
    bf16x8 kf0 = *(const bf16x8*)(ksl + (g ^ (ln & 7)) * 8);
    bf16x8 kf1 = *(const bf16x8*)(ksl + ((4 + g) ^ (ln & 7)) * 8);
    WAITL();                       // fragments in VGPRs; slot tt%3 reusable
    if (tt + 3 < 16) STAGE_K(tt + 3);
    SB();
    PRIO1();
    sc[tt] = __builtin_amdgcn_mfma_f32_16x16x32_bf16(kf0, qf[0], sc[tt], 0, 0, 0);
    sc[tt] = __builtin_amdgcn_mfma_f32_16x16x32_bf16(kf1, qf[1], sc[tt], 0, 0, 0);
    PRIO0();
  }

  // ---- mask loads (in flight while V stages issue / softmax starts) ----
  unsigned mw[16];
  {
    const unsigned char* mrow =
        masks + ((size_t)b * 1024 + m0 + wm * 16 + ln) * 1024 + wq * 16 + g * 4;
#pragma unroll
    for (int tt = 0; tt < 16; ++tt) mw[tt] = *(const unsigned*)(mrow + tt * 64);
  }
  SB();

  LBAR();                       // all waves past QK; K regions reusable for V
  STAGE_V(0); STAGE_V(1);       // V latency hides under softmax
  SB();

  // ---- softmax, ONE barrier (rows lane-local: q-row = ln) ----
  const float C = 0.18033688011112042f;   // 0.125 * log2(e)
  float mx = -3.0e30f;
#pragma unroll
  for (int tt = 0; tt < 16; ++tt) {
    if (mw[tt]) {
#pragma unroll
      for (int r = 0; r < 4; ++r)
        if ((mw[tt] >> (8 * r)) & 0xffu) sc[tt][r] = -1.0e30f;
    }
#pragma unroll
    for (int r = 0; r < 4; ++r) mx = fmaxf(mx, sc[tt][r]);
  }
  mx = fmaxf(mx, __shfl_xor(mx, 16));
  mx = fmaxf(mx, __shfl_xor(mx, 32));     // mx = this wave's row max
  const float mtl = mx * C;
  float sum = 0.f;                        // partial sum with LOCAL max
#pragma unroll
  for (int tt = 0; tt < 16; ++tt)
#pragma unroll
    for (int r = 0; r < 4; ++r)
      sum += exp2f(__builtin_fmaf(sc[tt][r], C, -mtl));
  sum += __shfl_xor(sum, 16);
  sum += __shfl_xor(sum, 32);
  if (g == 0) { red[0][wm][ln][wq] = mx; red[1][wm][ln][wq] = sum; }
  LBAR();
  float m4 = fmaxf(fmaxf(red[0][wm][ln][0], red[0][wm][ln][1]),
                   fmaxf(red[0][wm][ln][2], red[0][wm][ln][3]));
  float l4 = 0.f;
#pragma unroll
  for (int i = 0; i < 4; ++i)
    l4 += red[1][wm][ln][i] * exp2f((red[0][wm][ln][i] - m4) * C);
  // P = exp2(s*C + beta), beta folds global max AND normalization
  const float beta = __builtin_fmaf(-m4, C, -__builtin_log2f(l4));

  // ---- normalized bf16 P fragments (also the attention output values) ----
  bf16x8 af8[8];
#pragma unroll
  for (int c = 0; c < 8; ++c) {
    bf16x8 a;
#pragma unroll
    for (int r = 0; r < 4; ++r)
      a[r] = (short)f2bf(exp2f(__builtin_fmaf(sc[2 * c][r], C, beta)));
#pragma unroll
    for (int r = 0; r < 4; ++r)
      a[4 + r] = (short)f2bf(exp2f(__builtin_fmaf(sc[2 * c + 1][r], C, beta)));
    af8[c] = a;
  }

  // ---- PV + interleaved attention stores ----
  // issue order/iter: [waitv][BAR][STAGE_V(c+2)][4 MFMA][2 stores]
  // in-order vmcnt: younger-than-V(c) = {2,4,6,6,6,6,6,4} for c=0..7
  f32x4 cacc[4];
#pragma unroll
  for (int i = 0; i < 4; ++i) cacc[i] = {0.f, 0.f, 0.f, 0.f};
  const size_t abase =
      ((size_t)(b * 16 + h) * 1024 + (m0 + wm * 16 + ln)) * 1024 + wq * 16 + g * 4;
#pragma unroll
  for (int c = 0; c < 8; ++c) {
    waitv(c == 0 ? 2 : (c == 1 ? 4 : (c <= 6 ? 6 : 4)));
    BAR();
    if (c + 2 < 8) STAGE_V(c + 2);
    SB();
#pragma unroll
    for (int ni = 0; ni < 4; ++ni) {
      const int d = ni * 16 + ln;
      const int u0 = (2 * wq + (g >> 1)) ^ (ln & 7);
      const int u1 = (8 + 2 * wq + (g >> 1)) ^ (ln & 7);
      bf16x4 b0 = *(const bf16x4*)&sm.Vb[c % 3][d][u0 * 8 + (g & 1) * 4];
      bf16x4 b1 = *(const bf16x4*)&sm.Vb[c % 3][d][u1 * 8 + (g & 1) * 4];
      bf16x8 bfr = { b0[0], b0[1], b0[2], b0[3], b1[0], b1[1], b1[2], b1[3] };
      PRIO1();
      cacc[ni] = __builtin_amdgcn_mfma_f32_16x16x32_bf16(af8[c], bfr, cacc[ni], 0, 0, 0);
      PRIO0();
    }
    SB();
#pragma unroll
    for (int hf = 0; hf < 2; ++hf) {
      f32x4 v = { bf2f((unsigned short)af8[c][hf * 4 + 0]),
                  bf2f((unsigned short)af8[c][hf * 4 + 1]),
                  bf2f((unsigned short)af8[c][hf * 4 + 2]),
                  bf2f((unsigned short)af8[c][hf * 4 + 3]) };
      *(f32x4*)(attn_out + abase + (2 * c + hf) * 64) = v;
    }
    SB();
  }

  // ---- cross-wave ctx reduction + residual -> d_out ----
  LBAR();                       // all Vb reads done; reuse as ctxp
#pragma unroll
  for (int ni = 0; ni < 4; ++ni)
#pragma unroll
    for (int r = 0; r < 4; ++r)
      sm.ctxp[wq][wm * 16 + g * 4 + r][ni * 16 + ln] = cacc[ni][r];
  LBAR();
  {
    const int m = t >> 4, d4 = (t & 15) * 4;
    f32x4 s0 = *(const f32x4*)&sm.ctxp[0][m][d4];
    f32x4 s1 = *(const f32x4*)&sm.ctxp[1][m][d4];
    f32x4 s2 = *(const f32x4*)&sm.ctxp[2][m][d4];
    f32x4 s3 = *(const f32x4*)&sm.ctxp[3][m][d4];
    f32x4 s = s0 + s1 + s2 + s3;
    const unsigned short* qrow = qp + (rowbase + m) * 1024 + h * 64 + d4;
    u16x4 qv = *(const u16x4*)qrow;
    f32x4 qf32 = { bf2f(qv[0]), bf2f(qv[1]), bf2f(qv[2]), bf2f(qv[3]) };
    s = s + qf32;
    *(f32x4*)(res_out + (rowbase + m) * 1024 + h * 64 + d4) = s;
  }
#undef STAGE_K
#undef STAGE_V
}

// ---------------------------------------------------------------------------
// In-place LayerNorm on d_out[:B*L*D]: out = LN(out) * g + b, one block/row.
// ---------------------------------------------------------------------------
__global__ __launch_bounds__(256) void ln_kernel(
    float* __restrict__ io,
    const float* __restrict__ gma, const float* __restrict__ bta)
{
  __shared__ float rbuf[2][4];
  const int r = blockIdx.x, t = threadIdx.x;
  const int i4 = t * 4;
  const size_t base = (size_t)r * 1024 + i4;
  f32x4 x = *(const f32x4*)(io + base);
  float s = x[0] + x[1] + x[2] + x[3];
  float q = x[0]*x[0] + x[1]*x[1] + x[2]*x[2] + x[3]*x[3];
#pragma unroll
  for (int off = 1; off < 64; off <<= 1) {
    s += __shfl_xor(s, off);
    q += __shfl_xor(q, off);
  }
  const int wv = t >> 6;
  if ((t & 63) == 0) { rbuf[0][wv] = s; rbuf[1][wv] = q; }
  __syncthreads();
  s = rbuf[0][0] + rbuf[0][1] + rbuf[0][2] + rbuf[0][3];
  q = rbuf[1][0] + rbuf[1][1] + rbuf[1][2] + rbuf[1][3];
  float mu = s * (1.0f / 1024.0f);
  float var = q * (1.0f / 1024.0f) - mu * mu;
  float is = rsqrtf(var + 1e-6f);
  f32x4 gv = *(const f32x4*)(gma + i4);
  f32x4 bv = *(const f32x4*)(bta + i4);
  f32x4 o;
#pragma unroll
  for (int k = 0; k < 4; ++k) o[k] = (x[k] - mu) * is * gv[k] + bv[k];
  *(f32x4*)(io + base) = o;
}

// ---------------------------------------------------------------------------
extern "C" void kernel_launch(void* const* d_in, const int* in_sizes, int n_in,
                              void* d_out, int out_size, void* d_ws, size_t ws_size,
                              hipStream_t stream) {
  const float* q  = (const float*)d_in[0];
  const float* k  = (const float*)d_in[1];
  const float* v  = (const float*)d_in[2];
  const unsigned char* masks = (const unsigned char*)d_in[3];
  const float* Wq = (const float*)d_in[4];
  const float* bq = (const float*)d_in[5];
  const float* Wk = (const float*)d_in[6];
  const float* bk = (const float*)d_in[7];
  const float* Wv = (const float*)d_in[8];
  const float* bv = (const float*)d_in[9];
  const float* lg = (const float*)d_in[10];
  const float* lb = (const float*)d_in[11];

  float* out = (float*)d_out;
  float* attn_out = out + (size_t)4 * 1024 * 1024;

  // bf16 input scratch lives in the attn region of d_out (overwritten later
  // by attn_kernel -- all reads happen in cvt/gemm, stream-ordered before).
  unsigned short* xq  = (unsigned short*)attn_out;
  unsigned short* xk  = xq + 4194304;
  unsigned short* xv  = xk + 4194304;
  unsigned short* wqb = xv + 4194304;
  unsigned short* wkb = wqb + 1048576;
  unsigned short* wvb = wkb + 1048576;

  // workspace: 24 MB (qp | kp | vt, all bf16 4M elems each)
  unsigned short* qp = (unsigned short*)d_ws;
  unsigned short* kp = qp + 4194304;
  unsigned short* vt = kp + 4194304;

  hipLaunchKernelGGL(cvt_kernel, dim3(7680), dim3(256), 0, stream,
                     q, k, v, Wq, Wk, Wv, xq, xk, xv, wqb, wkb, wvb);
  hipLaunchKernelGGL(gemm_kernel, dim3(768), dim3(512), 0, stream,
                     xq, xk, xv, wqb, wkb, wvb, bq, bk, bv, qp, kp, vt);
  hipLaunchKernelGGL(attn_kernel, dim3(2048), dim3(512), 0, stream,
                     qp, kp, vt, masks, attn_out, out);
  hipLaunchKernelGGL(ln_kernel, dim3(4096), dim3(256), 0, stream,
                     out, lg, lb);
}